// Round 1
// baseline (1154.721 us; speedup 1.0000x reference)
//
#include <hip/hip_runtime.h>
#include <math.h>

#define B_  2
#define T_  2048
#define D_  1024
#define H_  16
#define HD_ 64

// ---------------------------------------------------------------------------
// Classic fp32 tiled GEMM: C[M,N] = A[M,K] @ B[K,N] + bias[N]
// BM=BN=128, BK=16, 256 threads, 8x8 micro-tile per thread.
// M,N,K must be multiples of 128/128/16 (true for all our shapes).
// ---------------------------------------------------------------------------
__global__ __launch_bounds__(256) void sgemm_bias_kernel(
    const float* __restrict__ A, const float* __restrict__ Bw,
    const float* __restrict__ bias, float* __restrict__ C,
    int M, int N, int K)
{
    constexpr int BM = 128, BN = 128, BK = 16;
    __shared__ float As[BK][BM + 4];   // stored transposed: As[k][m]
    __shared__ float Bs[BK][BN + 4];   // Bs[k][n]

    const int tid = threadIdx.x;
    const int bm  = blockIdx.y, bn = blockIdx.x;
    const int tm  = tid >> 4;          // 0..15  (row group)
    const int tn  = tid & 15;          // 0..15  (col group)

    // global-load assignment
    const int ar = tid >> 2;           // 0..63  (A row within tile, +64 for 2nd)
    const int ac = (tid & 3) << 2;     // 0,4,8,12 (k offset)
    const int br = tid >> 5;           // 0..7   (B k-row, +8 for 2nd)
    const int bc = (tid & 31) << 2;    // 0..124 (col offset)

    const float* gA = A  + ((size_t)(bm * BM + ar)) * K + ac;
    const float* gB = Bw + ((size_t)br) * N + (size_t)bn * BN + bc;

    float acc[8][8];
    #pragma unroll
    for (int y = 0; y < 8; ++y)
        #pragma unroll
        for (int x = 0; x < 8; ++x) acc[y][x] = 0.f;

    for (int k0 = 0; k0 < K; k0 += BK) {
        float4 a0 = *(const float4*)(gA + k0);
        float4 a1 = *(const float4*)(gA + (size_t)64 * K + k0);
        float4 b0 = *(const float4*)(gB + (size_t)k0 * N);
        float4 b1 = *(const float4*)(gB + (size_t)(k0 + 8) * N);

        __syncthreads();   // previous iteration's compute done before overwrite
        As[ac + 0][ar] = a0.x; As[ac + 1][ar] = a0.y;
        As[ac + 2][ar] = a0.z; As[ac + 3][ar] = a0.w;
        As[ac + 0][ar + 64] = a1.x; As[ac + 1][ar + 64] = a1.y;
        As[ac + 2][ar + 64] = a1.z; As[ac + 3][ar + 64] = a1.w;
        *(float4*)&Bs[br][bc]     = b0;
        *(float4*)&Bs[br + 8][bc] = b1;
        __syncthreads();

        #pragma unroll
        for (int k = 0; k < BK; ++k) {
            float a[8], b[8];
            *(float4*)(a)     = *(const float4*)&As[k][tm * 8];
            *(float4*)(a + 4) = *(const float4*)&As[k][tm * 8 + 4];
            *(float4*)(b)     = *(const float4*)&Bs[k][tn * 8];
            *(float4*)(b + 4) = *(const float4*)&Bs[k][tn * 8 + 4];
            #pragma unroll
            for (int y = 0; y < 8; ++y)
                #pragma unroll
                for (int x = 0; x < 8; ++x)
                    acc[y][x] += a[y] * b[x];
        }
    }

    const int row0 = bm * BM + tm * 8;
    const int col0 = bn * BN + tn * 8;
    #pragma unroll
    for (int y = 0; y < 8; ++y) {
        float4 o0, o1;
        o0.x = acc[y][0] + bias[col0 + 0];
        o0.y = acc[y][1] + bias[col0 + 1];
        o0.z = acc[y][2] + bias[col0 + 2];
        o0.w = acc[y][3] + bias[col0 + 3];
        o1.x = acc[y][4] + bias[col0 + 4];
        o1.y = acc[y][5] + bias[col0 + 5];
        o1.z = acc[y][6] + bias[col0 + 6];
        o1.w = acc[y][7] + bias[col0 + 7];
        *(float4*)&C[(size_t)(row0 + y) * N + col0]     = o0;
        *(float4*)&C[(size_t)(row0 + y) * N + col0 + 4] = o1;
    }
}

// ---------------------------------------------------------------------------
// Periodic-sparse causal attention, one 64-lane wave per (b,h,i) query.
// Valid keys enumerated directly: j = i - t*p, t = 0..i/p  (always includes j=i).
// qkv layout: row (b*T+t) has 3*D floats: [q: h*64+e | k: 1024+h*64+e | v: 2048+...]
// Output ao: (B*T, D) with ao[b*T+i][h*64+e]  (i.e. (b,t,h,e) = reference layout)
// ---------------------------------------------------------------------------
__global__ __launch_bounds__(64) void attn_kernel(
    const float* __restrict__ qkv, const int* __restrict__ periods,
    float* __restrict__ ao)
{
    const int blk  = blockIdx.x;
    const int i    = blk & (T_ - 1);
    const int bh   = blk >> 11;           // T_ = 2048 = 1<<11
    const int h    = bh & (H_ - 1);
    const int b    = bh >> 4;             // H_ = 16
    const int lane = threadIdx.x;

    int p = periods[b * H_ + h];
    if (p < 1) p = 1;
    const int cnt = i / p + 1;

    __shared__ float sq[HD_];
    __shared__ float sw[T_];              // scores -> softmax weights

    const size_t rowstride = 3 * (size_t)D_;
    const float* qrow = qkv + (size_t)(b * T_ + i) * rowstride + h * HD_;
    sq[lane] = qrow[lane];
    __syncthreads();

    const float* kbase = qkv + (size_t)b * T_ * rowstride + D_ + h * HD_;

    // ---- phase 1: scores for all valid keys ----
    for (int t = lane; t < cnt; t += 64) {
        const int j = i - t * p;
        const float* krow = kbase + (size_t)j * rowstride;
        float s = 0.f;
        #pragma unroll
        for (int d4 = 0; d4 < HD_; d4 += 4) {
            float4 kv = *(const float4*)(krow + d4);
            float4 qv = *(const float4*)(sq + d4);
            s += qv.x * kv.x + qv.y * kv.y + qv.z * kv.z + qv.w * kv.w;
        }
        sw[t] = s * 0.125f;               // 1/sqrt(64)
    }
    __syncthreads();

    // ---- phase 2: online-free softmax (two-pass, wave shuffle reduce) ----
    float m = -INFINITY;
    for (int t = lane; t < cnt; t += 64) m = fmaxf(m, sw[t]);
    #pragma unroll
    for (int off = 32; off; off >>= 1) m = fmaxf(m, __shfl_xor(m, off));

    float lsum = 0.f;
    for (int t = lane; t < cnt; t += 64) {
        float w = __expf(sw[t] - m);
        sw[t] = w;
        lsum += w;
    }
    #pragma unroll
    for (int off = 32; off; off >>= 1) lsum += __shfl_xor(lsum, off);
    const float rsum = 1.f / lsum;
    __syncthreads();

    // ---- phase 3: out[d=lane] = sum_t w[t] * v[j_t][lane]  (coalesced v reads) ----
    const float* vbase = qkv + (size_t)b * T_ * rowstride + 2 * D_ + h * HD_ + lane;
    float acc = 0.f;
    int t = 0;
    for (; t + 4 <= cnt; t += 4) {
        const int j0 = i - t * p;
        acc += sw[t + 0] * vbase[(size_t)(j0        ) * rowstride];
        acc += sw[t + 1] * vbase[(size_t)(j0 -     p) * rowstride];
        acc += sw[t + 2] * vbase[(size_t)(j0 - 2 * p) * rowstride];
        acc += sw[t + 3] * vbase[(size_t)(j0 - 3 * p) * rowstride];
    }
    for (; t < cnt; ++t)
        acc += sw[t] * vbase[(size_t)(i - t * p) * rowstride];

    ao[(size_t)(b * T_ + i) * D_ + h * HD_ + lane] = acc * rsum;
}

// ---------------------------------------------------------------------------
extern "C" void kernel_launch(void* const* d_in, const int* in_sizes, int n_in,
                              void* d_out, int out_size, void* d_ws, size_t ws_size,
                              hipStream_t stream)
{
    const float* x       = (const float*)d_in[0];
    const int*   periods = (const int*)  d_in[1];
    const float* w_qkv   = (const float*)d_in[2];
    const float* b_qkv   = (const float*)d_in[3];
    const float* w_out   = (const float*)d_in[4];
    const float* b_out   = (const float*)d_in[5];
    float*       out     = (float*)d_out;

    float* qkv = (float*)d_ws;                       // (4096, 3072) = 48 MB
    float* ao  = qkv + (size_t)(B_ * T_) * 3 * D_;   // (4096, 1024) = 16 MB

    const int M = B_ * T_;          // 4096

    // 1) qkv = x @ w_qkv + b_qkv     (4096 x 3072 x 1024)
    sgemm_bias_kernel<<<dim3((3 * D_) / 128, M / 128), 256, 0, stream>>>(
        x, w_qkv, b_qkv, qkv, M, 3 * D_, D_);

    // 2) periodic sparse attention -> ao (B*T, D)
    attn_kernel<<<B_ * H_ * T_, 64, 0, stream>>>(qkv, periods, ao);

    // 3) out = ao @ w_out + b_out    (4096 x 1024 x 1024)
    sgemm_bias_kernel<<<dim3(D_ / 128, M / 128), 256, 0, stream>>>(
        ao, w_out, b_out, out, M, D_, D_);
}

// Round 2
// 706.927 us; speedup vs baseline: 1.6334x; 1.6334x over previous
//
#include <hip/hip_runtime.h>
#include <math.h>

#define B_  2
#define T_  2048
#define D_  1024
#define H_  16
#define HD_ 64

// ---------------------------------------------------------------------------
// Classic fp32 tiled GEMM: C[M,N] = A[M,K] @ B[K,N] + bias[N]
// BM=BN=128, BK=16, 256 threads, 8x8 micro-tile per thread.
// ---------------------------------------------------------------------------
__global__ __launch_bounds__(256) void sgemm_bias_kernel(
    const float* __restrict__ A, const float* __restrict__ Bw,
    const float* __restrict__ bias, float* __restrict__ C,
    int M, int N, int K)
{
    constexpr int BM = 128, BN = 128, BK = 16;
    __shared__ float As[BK][BM + 4];   // stored transposed: As[k][m]
    __shared__ float Bs[BK][BN + 4];   // Bs[k][n]

    const int tid = threadIdx.x;
    const int bm  = blockIdx.y, bn = blockIdx.x;
    const int tm  = tid >> 4;          // 0..15
    const int tn  = tid & 15;          // 0..15

    const int ar = tid >> 2;           // 0..63
    const int ac = (tid & 3) << 2;     // 0,4,8,12
    const int br = tid >> 5;           // 0..7
    const int bc = (tid & 31) << 2;    // 0..124

    const float* gA = A  + ((size_t)(bm * BM + ar)) * K + ac;
    const float* gB = Bw + ((size_t)br) * N + (size_t)bn * BN + bc;

    float acc[8][8];
    #pragma unroll
    for (int y = 0; y < 8; ++y)
        #pragma unroll
        for (int x = 0; x < 8; ++x) acc[y][x] = 0.f;

    for (int k0 = 0; k0 < K; k0 += BK) {
        float4 a0 = *(const float4*)(gA + k0);
        float4 a1 = *(const float4*)(gA + (size_t)64 * K + k0);
        float4 b0 = *(const float4*)(gB + (size_t)k0 * N);
        float4 b1 = *(const float4*)(gB + (size_t)(k0 + 8) * N);

        __syncthreads();
        As[ac + 0][ar] = a0.x; As[ac + 1][ar] = a0.y;
        As[ac + 2][ar] = a0.z; As[ac + 3][ar] = a0.w;
        As[ac + 0][ar + 64] = a1.x; As[ac + 1][ar + 64] = a1.y;
        As[ac + 2][ar + 64] = a1.z; As[ac + 3][ar + 64] = a1.w;
        *(float4*)&Bs[br][bc]     = b0;
        *(float4*)&Bs[br + 8][bc] = b1;
        __syncthreads();

        #pragma unroll
        for (int k = 0; k < BK; ++k) {
            float a[8], b[8];
            *(float4*)(a)     = *(const float4*)&As[k][tm * 8];
            *(float4*)(a + 4) = *(const float4*)&As[k][tm * 8 + 4];
            *(float4*)(b)     = *(const float4*)&Bs[k][tn * 8];
            *(float4*)(b + 4) = *(const float4*)&Bs[k][tn * 8 + 4];
            #pragma unroll
            for (int y = 0; y < 8; ++y)
                #pragma unroll
                for (int x = 0; x < 8; ++x)
                    acc[y][x] += a[y] * b[x];
        }
    }

    const int row0 = bm * BM + tm * 8;
    const int col0 = bn * BN + tn * 8;
    #pragma unroll
    for (int y = 0; y < 8; ++y) {
        float4 o0, o1;
        o0.x = acc[y][0] + bias[col0 + 0];
        o0.y = acc[y][1] + bias[col0 + 1];
        o0.z = acc[y][2] + bias[col0 + 2];
        o0.w = acc[y][3] + bias[col0 + 3];
        o1.x = acc[y][4] + bias[col0 + 4];
        o1.y = acc[y][5] + bias[col0 + 5];
        o1.z = acc[y][6] + bias[col0 + 6];
        o1.w = acc[y][7] + bias[col0 + 7];
        *(float4*)&C[(size_t)(row0 + y) * N + col0]     = o0;
        *(float4*)&C[(size_t)(row0 + y) * N + col0 + 4] = o1;
    }
}

// ---------------------------------------------------------------------------
// Periodic-sparse attention = p independent dense causal attentions on the
// residue-class subsequences (i ≡ r mod p). Flash-style tiles of 64 queries ×
// 64 keys; 256 threads as a 16(q-group) × 16(k/d-group) grid, 4×4 micro-tiles.
// qkv row (b*T+t): [q | k | v] each D floats, head h at offset h*64.
// ---------------------------------------------------------------------------
__global__ __launch_bounds__(256) void attn_tiled_kernel(
    const float* __restrict__ qkv, const int* __restrict__ periods,
    float* __restrict__ ao)
{
    __shared__ float Qs[64][64];    // [d][q]  (transposed)
    __shared__ float KVs[64][64];   // K-phase: [d][k] (transposed); V-phase: [k][d]
    __shared__ float Ps[64][68];    // [q][k], stride 68 breaks bank aliasing

    const int bh = blockIdx.y;      // 0..31
    const int h  = bh & (H_ - 1);
    const int b  = bh >> 4;
    int p = periods[bh]; if (p < 1) p = 1;

    // map blockIdx.x -> (residue class r, query tile q0) ; excess blocks exit
    int tidx = blockIdx.x;
    int r = -1, q0 = 0, nr = 0;
    for (int rr = 0; rr < p; ++rr) {
        const int n  = (T_ - 1 - rr) / p + 1;   // queries in class rr
        const int nt = (n + 63) >> 6;
        if (tidx < nt) { r = rr; nr = n; q0 = tidx << 6; break; }
        tidx -= nt;
    }
    if (r < 0) return;
    const int qn = min(64, nr - q0);            // valid queries in this tile

    const int tid = threadIdx.x;
    const int qg  = tid >> 4;                   // 0..15 query group
    const int kg  = tid & 15;                   // 0..15 key/dim group

    const size_t rowstride = 3 * (size_t)D_;
    const float* base = qkv + (size_t)b * T_ * rowstride + h * HD_;

    // ---- stage Q tile, transposed ----
    {
        const int qq = tid >> 2, quarter = tid & 3;
        const int qi = min(q0 + qq, nr - 1);
        const float* qrow = base + (size_t)(r + qi * p) * rowstride;
        #pragma unroll
        for (int c = 0; c < 4; ++c) {
            const int d = (quarter * 4 + c) * 4;
            float4 v = *(const float4*)(qrow + d);
            Qs[d + 0][qq] = v.x; Qs[d + 1][qq] = v.y;
            Qs[d + 2][qq] = v.z; Qs[d + 3][qq] = v.w;
        }
    }

    float O[4][4];
    float m_i[4], l_i[4];
    #pragma unroll
    for (int ii = 0; ii < 4; ++ii) {
        m_i[ii] = -INFINITY; l_i[ii] = 0.f;
        #pragma unroll
        for (int jj = 0; jj < 4; ++jj) O[ii][jj] = 0.f;
    }

    const int kts = (q0 + qn + 63) >> 6;
    for (int kt = 0; kt < kts; ++kt) {
        const int k0 = kt << 6;

        // ---- stage K tile, transposed ----
        __syncthreads();
        {
            const int kk = tid >> 2, quarter = tid & 3;
            const int kj = min(k0 + kk, nr - 1);
            const float* krow = base + D_ + (size_t)(r + kj * p) * rowstride;
            #pragma unroll
            for (int c = 0; c < 4; ++c) {
                const int d = (quarter * 4 + c) * 4;
                float4 v = *(const float4*)(krow + d);
                KVs[d + 0][kk] = v.x; KVs[d + 1][kk] = v.y;
                KVs[d + 2][kk] = v.z; KVs[d + 3][kk] = v.w;
            }
        }
        __syncthreads();

        // ---- S = Q K^T (4x4 per thread) ----
        float S[4][4];
        #pragma unroll
        for (int ii = 0; ii < 4; ++ii)
            #pragma unroll
            for (int jj = 0; jj < 4; ++jj) S[ii][jj] = 0.f;

        #pragma unroll 8
        for (int d = 0; d < 64; ++d) {
            float4 a4 = *(const float4*)&Qs[d][qg * 4];
            float4 b4 = *(const float4*)&KVs[d][kg * 4];
            const float* a = (const float*)&a4;
            const float* bb = (const float*)&b4;
            #pragma unroll
            for (int ii = 0; ii < 4; ++ii)
                #pragma unroll
                for (int jj = 0; jj < 4; ++jj)
                    S[ii][jj] += a[ii] * bb[jj];
        }

        // ---- scale + causal mask + online softmax ----
        const bool need_mask = (k0 + 64 > q0);
        #pragma unroll
        for (int ii = 0; ii < 4; ++ii) {
            const int qabs = q0 + 4 * qg + ii;
            #pragma unroll
            for (int jj = 0; jj < 4; ++jj) {
                float s = S[ii][jj] * 0.125f;   // 1/sqrt(64)
                if (need_mask) {
                    const int kabs = k0 + 4 * kg + jj;
                    if (kabs > qabs) s = -INFINITY;
                }
                S[ii][jj] = s;
            }
        }

        #pragma unroll
        for (int ii = 0; ii < 4; ++ii) {
            float v = fmaxf(fmaxf(S[ii][0], S[ii][1]), fmaxf(S[ii][2], S[ii][3]));
            v = fmaxf(v, __shfl_xor(v, 1));
            v = fmaxf(v, __shfl_xor(v, 2));
            v = fmaxf(v, __shfl_xor(v, 4));
            v = fmaxf(v, __shfl_xor(v, 8));
            const float newm = fmaxf(m_i[ii], v);
            const float alpha = (newm == -INFINITY) ? 0.f : __expf(m_i[ii] - newm);
            m_i[ii] = newm;
            l_i[ii] *= alpha;
            #pragma unroll
            for (int jj = 0; jj < 4; ++jj) O[ii][jj] *= alpha;

            float4 e;
            float* ep = (float*)&e;
            #pragma unroll
            for (int jj = 0; jj < 4; ++jj)
                ep[jj] = (newm == -INFINITY) ? 0.f : __expf(S[ii][jj] - newm);
            float rs = ep[0] + ep[1] + ep[2] + ep[3];
            rs += __shfl_xor(rs, 1);
            rs += __shfl_xor(rs, 2);
            rs += __shfl_xor(rs, 4);
            rs += __shfl_xor(rs, 8);
            l_i[ii] += rs;
            *(float4*)&Ps[4 * qg + ii][4 * kg] = e;
        }
        __syncthreads();   // Ps visible; done reading KVs as K

        // ---- stage V tile (natural layout) ----
        {
            const int kk = tid >> 2, quarter = tid & 3;
            const int kj = min(k0 + kk, nr - 1);
            const float* vrow = base + 2 * D_ + (size_t)(r + kj * p) * rowstride;
            #pragma unroll
            for (int c = 0; c < 4; ++c) {
                const int d = (quarter * 4 + c) * 4;
                *(float4*)&KVs[kk][d] = *(const float4*)(vrow + d);
            }
        }
        __syncthreads();

        // ---- O += P V ----
        #pragma unroll 4
        for (int kj4 = 0; kj4 < 64; kj4 += 4) {
            float4 pv0 = *(const float4*)&Ps[4 * qg + 0][kj4];
            float4 pv1 = *(const float4*)&Ps[4 * qg + 1][kj4];
            float4 pv2 = *(const float4*)&Ps[4 * qg + 2][kj4];
            float4 pv3 = *(const float4*)&Ps[4 * qg + 3][kj4];
            const float* p0 = (const float*)&pv0;
            const float* p1 = (const float*)&pv1;
            const float* p2 = (const float*)&pv2;
            const float* p3 = (const float*)&pv3;
            #pragma unroll
            for (int c = 0; c < 4; ++c) {
                float4 v4 = *(const float4*)&KVs[kj4 + c][4 * kg];
                const float* vv = (const float*)&v4;
                #pragma unroll
                for (int jj = 0; jj < 4; ++jj) {
                    O[0][jj] += p0[c] * vv[jj];
                    O[1][jj] += p1[c] * vv[jj];
                    O[2][jj] += p2[c] * vv[jj];
                    O[3][jj] += p3[c] * vv[jj];
                }
            }
        }
    }

    // ---- normalize + store ----
    #pragma unroll
    for (int ii = 0; ii < 4; ++ii) {
        const int qq = 4 * qg + ii;
        if (qq < qn) {
            const int i = r + (q0 + qq) * p;
            const float inv = 1.f / l_i[ii];
            float4 o;
            o.x = O[ii][0] * inv; o.y = O[ii][1] * inv;
            o.z = O[ii][2] * inv; o.w = O[ii][3] * inv;
            *(float4*)&ao[(size_t)(b * T_ + i) * D_ + h * HD_ + 4 * kg] = o;
        }
    }
}

// ---------------------------------------------------------------------------
extern "C" void kernel_launch(void* const* d_in, const int* in_sizes, int n_in,
                              void* d_out, int out_size, void* d_ws, size_t ws_size,
                              hipStream_t stream)
{
    const float* x       = (const float*)d_in[0];
    const int*   periods = (const int*)  d_in[1];
    const float* w_qkv   = (const float*)d_in[2];
    const float* b_qkv   = (const float*)d_in[3];
    const float* w_out   = (const float*)d_in[4];
    const float* b_out   = (const float*)d_in[5];
    float*       out     = (float*)d_out;

    float* qkv = (float*)d_ws;                       // (4096, 3072) = 48 MB
    float* ao  = qkv + (size_t)(B_ * T_) * 3 * D_;   // (4096, 1024) = 16 MB

    const int M = B_ * T_;          // 4096

    // 1) qkv = x @ w_qkv + b_qkv     (4096 x 3072 x 1024)
    sgemm_bias_kernel<<<dim3((3 * D_) / 128, M / 128), 256, 0, stream>>>(
        x, w_qkv, b_qkv, qkv, M, 3 * D_, D_);

    // 2) periodic sparse attention -> ao (B*T, D)
    //    48 tiles/head covers worst case (p=15 -> 45); excess blocks exit.
    attn_tiled_kernel<<<dim3(48, B_ * H_), 256, 0, stream>>>(qkv, periods, ao);

    // 3) out = ao @ w_out + b_out    (4096 x 1024 x 1024)
    sgemm_bias_kernel<<<dim3(D_ / 128, M / 128), 256, 0, stream>>>(
        ao, w_out, b_out, out, M, D_, D_);
}

// Round 3
// 361.844 us; speedup vs baseline: 3.1912x; 1.9537x over previous
//
#include <hip/hip_runtime.h>
#include <math.h>

#define B_  2
#define T_  2048
#define D_  1024
#define H_  16
#define HD_ 64

typedef float    f32x4  __attribute__((ext_vector_type(4)));
typedef _Float16 half8  __attribute__((ext_vector_type(8)));
typedef _Float16 half4v __attribute__((ext_vector_type(4)));

#define GLOAD_LDS16(g, l)                                                     \
    __builtin_amdgcn_global_load_lds(                                         \
        (__attribute__((address_space(1))) void*)(g),                         \
        (__attribute__((address_space(3))) void*)(l), 16, 0, 0)

// ---------------------------------------------------------------------------
// cast fp32 -> fp16, 4 elems/thread
// ---------------------------------------------------------------------------
__global__ __launch_bounds__(256) void cast_f32_f16_kernel(
    const float* __restrict__ in, _Float16* __restrict__ out, int n)
{
    const int i = (blockIdx.x * 256 + threadIdx.x) * 4;
    if (i + 3 < n) {
        float4 v = *(const float4*)(in + i);
        half4v h;
        h[0] = (_Float16)v.x; h[1] = (_Float16)v.y;
        h[2] = (_Float16)v.z; h[3] = (_Float16)v.w;
        *(half4v*)(out + i) = h;
    }
}

// ---------------------------------------------------------------------------
// transpose + cast: in[R][C] fp32 -> out[C][R] fp16.  R,C multiples of 32.
// ---------------------------------------------------------------------------
__global__ __launch_bounds__(256) void transpose_cast_kernel(
    const float* __restrict__ in, _Float16* __restrict__ out, int R, int C)
{
    __shared__ float tile[32][33];
    const int c0 = blockIdx.x * 32, r0 = blockIdx.y * 32;
    const int tx = threadIdx.x & 31, ty = threadIdx.x >> 5;   // 32 x 8
    #pragma unroll
    for (int q = 0; q < 4; ++q)
        tile[ty + 8 * q][tx] = in[(size_t)(r0 + ty + 8 * q) * C + c0 + tx];
    __syncthreads();
    #pragma unroll
    for (int q = 0; q < 4; ++q)
        out[(size_t)(c0 + ty + 8 * q) * R + r0 + tx] = (_Float16)tile[tx][ty + 8 * q];
}

// ---------------------------------------------------------------------------
// f16 MFMA GEMM:  C[M][N] = A[M][K] @ Bt[N][K]^T + bias   (all dims %128==0,
// K%32==0).  128x128 tile, BK=32, 256 thr = 4 waves, 4x4 16x16x32 MFMA/wave.
// global->LDS via global_load_lds width 16 (m97 structure).
// ---------------------------------------------------------------------------
template <typename OutT>
__global__ __launch_bounds__(256) void gemm_bt_f16(
    const _Float16* __restrict__ A, const _Float16* __restrict__ Bt,
    const float* __restrict__ bias, OutT* __restrict__ C,
    int M, int N, int K)
{
    __shared__ __align__(16) _Float16 As[128 * 32];
    __shared__ __align__(16) _Float16 Bs[128 * 32];

    const int tid  = threadIdx.x;
    const int lane = tid & 63;
    const int w    = tid >> 6;            // wave 0..3
    const int wm   = (w >> 1) * 64;       // wave's row block in tile
    const int wn   = (w & 1) * 64;        // wave's col block in tile

    // staging: each wave fills rows [w*32, w*32+32) of As and Bs
    const int srow  = lane >> 2;          // 0..15
    const int skoff = (lane & 3) * 8;     // 0,8,16,24 (halves)

    const _Float16* gA = A  + (size_t)(blockIdx.y * 128 + w * 32 + srow) * K + skoff;
    const _Float16* gB = Bt + (size_t)(blockIdx.x * 128 + w * 32 + srow) * K + skoff;
    _Float16* lA0 = &As[(w * 32 +  0) * 32];
    _Float16* lA1 = &As[(w * 32 + 16) * 32];
    _Float16* lB0 = &Bs[(w * 32 +  0) * 32];
    _Float16* lB1 = &Bs[(w * 32 + 16) * 32];

    f32x4 acc[4][4];
    #pragma unroll
    for (int i = 0; i < 4; ++i)
        #pragma unroll
        for (int j = 0; j < 4; ++j)
            #pragma unroll
            for (int r = 0; r < 4; ++r) acc[i][j][r] = 0.f;

    const int fr = lane & 15;             // MFMA m / n index
    const int fq = lane >> 4;             // MFMA k-quad

    for (int k0 = 0; k0 < K; k0 += 32) {
        GLOAD_LDS16(gA + k0,              lA0);
        GLOAD_LDS16(gA + 16 * (size_t)K + k0, lA1);
        GLOAD_LDS16(gB + k0,              lB0);
        GLOAD_LDS16(gB + 16 * (size_t)K + k0, lB1);
        __syncthreads();    // vmcnt(0) drain: LDS tiles complete

        half8 af[4], bf[4];
        #pragma unroll
        for (int i = 0; i < 4; ++i)
            af[i] = *(const half8*)&As[(wm + i * 16 + fr) * 32 + fq * 8];
        #pragma unroll
        for (int j = 0; j < 4; ++j)
            bf[j] = *(const half8*)&Bs[(wn + j * 16 + fr) * 32 + fq * 8];

        #pragma unroll
        for (int i = 0; i < 4; ++i)
            #pragma unroll
            for (int j = 0; j < 4; ++j)
                acc[i][j] = __builtin_amdgcn_mfma_f32_16x16x32_f16(
                    af[i], bf[j], acc[i][j], 0, 0, 0);
        __syncthreads();    // all reads done before next staging overwrites
    }

    // epilogue: D row = fq*4+reg, col = fr
    #pragma unroll
    for (int j = 0; j < 4; ++j) {
        const int col = blockIdx.x * 128 + wn + j * 16 + fr;
        const float bv = bias[col];
        #pragma unroll
        for (int i = 0; i < 4; ++i) {
            const int row = blockIdx.y * 128 + wm + i * 16 + fq * 4;
            #pragma unroll
            for (int r = 0; r < 4; ++r)
                C[(size_t)(row + r) * N + col] = (OutT)(acc[i][j][r] + bv);
        }
    }
}

// ---------------------------------------------------------------------------
// Periodic-sparse attention = p independent dense causal attentions on the
// residue-class subsequences (i ≡ r mod p). 64q x 64k flash tiles, fp16 in,
// fp32 compute, fp16 out.  256 thr = 16(qg) x 16(kg), 4x4 micro-tiles.
// ---------------------------------------------------------------------------
__global__ __launch_bounds__(256) void attn_tiled_kernel(
    const _Float16* __restrict__ qkv, const int* __restrict__ periods,
    _Float16* __restrict__ ao)
{
    __shared__ float Qs[64][64];    // [d][q]
    __shared__ float KVs[64][64];   // K-phase: [d][k]; V-phase: [k][d]
    __shared__ float Ps[64][68];    // [q][k]

    const int bh = blockIdx.y;
    const int h  = bh & (H_ - 1);
    const int b  = bh >> 4;
    int p = periods[bh]; if (p < 1) p = 1;

    int tidx = blockIdx.x;
    int r = -1, q0 = 0, nr = 0;
    for (int rr = 0; rr < p; ++rr) {
        const int n  = (T_ - 1 - rr) / p + 1;
        const int nt = (n + 63) >> 6;
        if (tidx < nt) { r = rr; nr = n; q0 = tidx << 6; break; }
        tidx -= nt;
    }
    if (r < 0) return;
    const int qn = min(64, nr - q0);

    const int tid = threadIdx.x;
    const int qg  = tid >> 4;
    const int kg  = tid & 15;

    const size_t rowstride = 3 * (size_t)D_;
    const _Float16* base = qkv + (size_t)b * T_ * rowstride + h * HD_;

    {   // stage Q (transposed)
        const int qq = tid >> 2, quarter = tid & 3;
        const int qi = min(q0 + qq, nr - 1);
        const _Float16* qrow = base + (size_t)(r + qi * p) * rowstride;
        #pragma unroll
        for (int c = 0; c < 4; ++c) {
            const int d = (quarter * 4 + c) * 4;
            half4v v = *(const half4v*)(qrow + d);
            Qs[d + 0][qq] = (float)v[0]; Qs[d + 1][qq] = (float)v[1];
            Qs[d + 2][qq] = (float)v[2]; Qs[d + 3][qq] = (float)v[3];
        }
    }

    float O[4][4];
    float m_i[4], l_i[4];
    #pragma unroll
    for (int ii = 0; ii < 4; ++ii) {
        m_i[ii] = -INFINITY; l_i[ii] = 0.f;
        #pragma unroll
        for (int jj = 0; jj < 4; ++jj) O[ii][jj] = 0.f;
    }

    const int kts = (q0 + qn + 63) >> 6;
    for (int kt = 0; kt < kts; ++kt) {
        const int k0 = kt << 6;

        __syncthreads();
        {   // stage K (transposed)
            const int kk = tid >> 2, quarter = tid & 3;
            const int kj = min(k0 + kk, nr - 1);
            const _Float16* krow = base + D_ + (size_t)(r + kj * p) * rowstride;
            #pragma unroll
            for (int c = 0; c < 4; ++c) {
                const int d = (quarter * 4 + c) * 4;
                half4v v = *(const half4v*)(krow + d);
                KVs[d + 0][kk] = (float)v[0]; KVs[d + 1][kk] = (float)v[1];
                KVs[d + 2][kk] = (float)v[2]; KVs[d + 3][kk] = (float)v[3];
            }
        }
        __syncthreads();

        float S[4][4];
        #pragma unroll
        for (int ii = 0; ii < 4; ++ii)
            #pragma unroll
            for (int jj = 0; jj < 4; ++jj) S[ii][jj] = 0.f;

        #pragma unroll 8
        for (int d = 0; d < 64; ++d) {
            float4 a4 = *(const float4*)&Qs[d][qg * 4];
            float4 b4 = *(const float4*)&KVs[d][kg * 4];
            const float* a  = (const float*)&a4;
            const float* bb = (const float*)&b4;
            #pragma unroll
            for (int ii = 0; ii < 4; ++ii)
                #pragma unroll
                for (int jj = 0; jj < 4; ++jj)
                    S[ii][jj] += a[ii] * bb[jj];
        }

        const bool need_mask = (k0 + 64 > q0);
        #pragma unroll
        for (int ii = 0; ii < 4; ++ii) {
            const int qabs = q0 + 4 * qg + ii;
            #pragma unroll
            for (int jj = 0; jj < 4; ++jj) {
                float s = S[ii][jj] * 0.125f;
                if (need_mask) {
                    const int kabs = k0 + 4 * kg + jj;
                    if (kabs > qabs) s = -INFINITY;
                }
                S[ii][jj] = s;
            }
        }

        #pragma unroll
        for (int ii = 0; ii < 4; ++ii) {
            float v = fmaxf(fmaxf(S[ii][0], S[ii][1]), fmaxf(S[ii][2], S[ii][3]));
            v = fmaxf(v, __shfl_xor(v, 1));
            v = fmaxf(v, __shfl_xor(v, 2));
            v = fmaxf(v, __shfl_xor(v, 4));
            v = fmaxf(v, __shfl_xor(v, 8));
            const float newm = fmaxf(m_i[ii], v);
            const float alpha = (newm == -INFINITY) ? 0.f : __expf(m_i[ii] - newm);
            m_i[ii] = newm;
            l_i[ii] *= alpha;
            #pragma unroll
            for (int jj = 0; jj < 4; ++jj) O[ii][jj] *= alpha;

            float4 e;
            float* ep = (float*)&e;
            #pragma unroll
            for (int jj = 0; jj < 4; ++jj)
                ep[jj] = (newm == -INFINITY) ? 0.f : __expf(S[ii][jj] - newm);
            float rs = ep[0] + ep[1] + ep[2] + ep[3];
            rs += __shfl_xor(rs, 1);
            rs += __shfl_xor(rs, 2);
            rs += __shfl_xor(rs, 4);
            rs += __shfl_xor(rs, 8);
            l_i[ii] += rs;
            *(float4*)&Ps[4 * qg + ii][4 * kg] = e;
        }
        __syncthreads();

        {   // stage V (natural layout)
            const int kk = tid >> 2, quarter = tid & 3;
            const int kj = min(k0 + kk, nr - 1);
            const _Float16* vrow = base + 2 * D_ + (size_t)(r + kj * p) * rowstride;
            #pragma unroll
            for (int c = 0; c < 4; ++c) {
                const int d = (quarter * 4 + c) * 4;
                half4v v = *(const half4v*)(vrow + d);
                KVs[kk][d + 0] = (float)v[0]; KVs[kk][d + 1] = (float)v[1];
                KVs[kk][d + 2] = (float)v[2]; KVs[kk][d + 3] = (float)v[3];
            }
        }
        __syncthreads();

        #pragma unroll 4
        for (int kj4 = 0; kj4 < 64; kj4 += 4) {
            float4 pv0 = *(const float4*)&Ps[4 * qg + 0][kj4];
            float4 pv1 = *(const float4*)&Ps[4 * qg + 1][kj4];
            float4 pv2 = *(const float4*)&Ps[4 * qg + 2][kj4];
            float4 pv3 = *(const float4*)&Ps[4 * qg + 3][kj4];
            const float* p0 = (const float*)&pv0;
            const float* p1 = (const float*)&pv1;
            const float* p2 = (const float*)&pv2;
            const float* p3 = (const float*)&pv3;
            #pragma unroll
            for (int c = 0; c < 4; ++c) {
                float4 v4 = *(const float4*)&KVs[kj4 + c][4 * kg];
                const float* vv = (const float*)&v4;
                #pragma unroll
                for (int jj = 0; jj < 4; ++jj) {
                    O[0][jj] += p0[c] * vv[jj];
                    O[1][jj] += p1[c] * vv[jj];
                    O[2][jj] += p2[c] * vv[jj];
                    O[3][jj] += p3[c] * vv[jj];
                }
            }
        }
    }

    #pragma unroll
    for (int ii = 0; ii < 4; ++ii) {
        const int qq = 4 * qg + ii;
        if (qq < qn) {
            const int i = r + (q0 + qq) * p;
            const float inv = 1.f / l_i[ii];
            half4v o;
            o[0] = (_Float16)(O[ii][0] * inv);
            o[1] = (_Float16)(O[ii][1] * inv);
            o[2] = (_Float16)(O[ii][2] * inv);
            o[3] = (_Float16)(O[ii][3] * inv);
            *(half4v*)&ao[(size_t)(b * T_ + i) * D_ + h * HD_ + 4 * kg] = o;
        }
    }
}

// ---------------------------------------------------------------------------
extern "C" void kernel_launch(void* const* d_in, const int* in_sizes, int n_in,
                              void* d_out, int out_size, void* d_ws, size_t ws_size,
                              hipStream_t stream)
{
    const float* x       = (const float*)d_in[0];
    const int*   periods = (const int*)  d_in[1];
    const float* w_qkv   = (const float*)d_in[2];
    const float* b_qkv   = (const float*)d_in[3];
    const float* w_out   = (const float*)d_in[4];
    const float* b_out   = (const float*)d_in[5];
    float*       out     = (float*)d_out;

    const int M = B_ * T_;                                  // 4096

    _Float16* x16   = (_Float16*)d_ws;                      // 8 MB
    _Float16* wqkvT = x16   + (size_t)M * D_;               // 6 MB  [3D][D]
    _Float16* qkv16 = wqkvT + (size_t)(3 * D_) * D_;        // 24 MB [M][3D]
    _Float16* ao16  = qkv16 + (size_t)M * 3 * D_;           // 8 MB  [M][D]
    _Float16* woutT = ao16  + (size_t)M * D_;               // 2 MB  [D][D]

    // prep: casts + weight transposes
    cast_f32_f16_kernel<<<(M * D_) / (256 * 4), 256, 0, stream>>>(x, x16, M * D_);
    transpose_cast_kernel<<<dim3((3 * D_) / 32, D_ / 32), 256, 0, stream>>>(
        w_qkv, wqkvT, D_, 3 * D_);
    transpose_cast_kernel<<<dim3(D_ / 32, D_ / 32), 256, 0, stream>>>(
        w_out, woutT, D_, D_);

    // 1) qkv = x @ w_qkv + b_qkv   (f16 MFMA, f16 out)
    gemm_bt_f16<_Float16><<<dim3((3 * D_) / 128, M / 128), 256, 0, stream>>>(
        x16, wqkvT, b_qkv, qkv16, M, 3 * D_, D_);

    // 2) periodic sparse attention -> ao16
    attn_tiled_kernel<<<dim3(48, B_ * H_), 256, 0, stream>>>(qkv16, periods, ao16);

    // 3) out = ao @ w_out + b_out  (f16 MFMA, fp32 out)
    gemm_bt_f16<float><<<dim3(D_ / 128, M / 128), 256, 0, stream>>>(
        ao16, woutT, b_out, out, M, D_, D_);
}

// Round 4
// 221.585 us; speedup vs baseline: 5.2112x; 1.6330x over previous
//
#include <hip/hip_runtime.h>
#include <math.h>

#define B_  2
#define T_  2048
#define D_  1024
#define H_  16
#define HD_ 64

typedef float    f32x4  __attribute__((ext_vector_type(4)));
typedef _Float16 half8  __attribute__((ext_vector_type(8)));
typedef _Float16 half4v __attribute__((ext_vector_type(4)));

#define GLOAD_LDS16(g, l)                                                     \
    __builtin_amdgcn_global_load_lds(                                         \
        (__attribute__((address_space(1))) void*)(g),                         \
        (__attribute__((address_space(3))) void*)(l), 16, 0, 0)

// ---------------------------------------------------------------------------
// cast fp32 -> fp16, 4 elems/thread
// ---------------------------------------------------------------------------
__global__ __launch_bounds__(256) void cast_f32_f16_kernel(
    const float* __restrict__ in, _Float16* __restrict__ out, int n)
{
    const int i = (blockIdx.x * 256 + threadIdx.x) * 4;
    if (i + 3 < n) {
        float4 v = *(const float4*)(in + i);
        half4v h;
        h[0] = (_Float16)v.x; h[1] = (_Float16)v.y;
        h[2] = (_Float16)v.z; h[3] = (_Float16)v.w;
        *(half4v*)(out + i) = h;
    }
}

// ---------------------------------------------------------------------------
// transpose + cast: in[R][C] fp32 -> out[C][R] fp16.  R,C multiples of 32.
// ---------------------------------------------------------------------------
__global__ __launch_bounds__(256) void transpose_cast_kernel(
    const float* __restrict__ in, _Float16* __restrict__ out, int R, int C)
{
    __shared__ float tile[32][33];
    const int c0 = blockIdx.x * 32, r0 = blockIdx.y * 32;
    const int tx = threadIdx.x & 31, ty = threadIdx.x >> 5;   // 32 x 8
    #pragma unroll
    for (int q = 0; q < 4; ++q)
        tile[ty + 8 * q][tx] = in[(size_t)(r0 + ty + 8 * q) * C + c0 + tx];
    __syncthreads();
    #pragma unroll
    for (int q = 0; q < 4; ++q)
        out[(size_t)(c0 + ty + 8 * q) * R + r0 + tx] = (_Float16)tile[tx][ty + 8 * q];
}

// ---------------------------------------------------------------------------
// f16 MFMA GEMM:  C[M][N] = A[M][K] @ Bt[N][K]^T + bias.  128x128 tile, BK=32,
// 256 thr = 4 waves, 4x4 16x16x32 MFMA/wave. global_load_lds width-16 staging.
// ---------------------------------------------------------------------------
template <typename OutT>
__global__ __launch_bounds__(256) void gemm_bt_f16(
    const _Float16* __restrict__ A, const _Float16* __restrict__ Bt,
    const float* __restrict__ bias, OutT* __restrict__ C,
    int M, int N, int K)
{
    __shared__ __align__(16) _Float16 As[128 * 32];
    __shared__ __align__(16) _Float16 Bs[128 * 32];

    const int tid  = threadIdx.x;
    const int lane = tid & 63;
    const int w    = tid >> 6;
    const int wm   = (w >> 1) * 64;
    const int wn   = (w & 1) * 64;

    const int srow  = lane >> 2;
    const int skoff = (lane & 3) * 8;

    const _Float16* gA = A  + (size_t)(blockIdx.y * 128 + w * 32 + srow) * K + skoff;
    const _Float16* gB = Bt + (size_t)(blockIdx.x * 128 + w * 32 + srow) * K + skoff;
    _Float16* lA0 = &As[(w * 32 +  0) * 32];
    _Float16* lA1 = &As[(w * 32 + 16) * 32];
    _Float16* lB0 = &Bs[(w * 32 +  0) * 32];
    _Float16* lB1 = &Bs[(w * 32 + 16) * 32];

    f32x4 acc[4][4];
    #pragma unroll
    for (int i = 0; i < 4; ++i)
        #pragma unroll
        for (int j = 0; j < 4; ++j)
            #pragma unroll
            for (int r = 0; r < 4; ++r) acc[i][j][r] = 0.f;

    const int fr = lane & 15;
    const int fq = lane >> 4;

    for (int k0 = 0; k0 < K; k0 += 32) {
        GLOAD_LDS16(gA + k0,                  lA0);
        GLOAD_LDS16(gA + 16 * (size_t)K + k0, lA1);
        GLOAD_LDS16(gB + k0,                  lB0);
        GLOAD_LDS16(gB + 16 * (size_t)K + k0, lB1);
        __syncthreads();

        half8 af[4], bf[4];
        #pragma unroll
        for (int i = 0; i < 4; ++i)
            af[i] = *(const half8*)&As[(wm + i * 16 + fr) * 32 + fq * 8];
        #pragma unroll
        for (int j = 0; j < 4; ++j)
            bf[j] = *(const half8*)&Bs[(wn + j * 16 + fr) * 32 + fq * 8];

        #pragma unroll
        for (int i = 0; i < 4; ++i)
            #pragma unroll
            for (int j = 0; j < 4; ++j)
                acc[i][j] = __builtin_amdgcn_mfma_f32_16x16x32_f16(
                    af[i], bf[j], acc[i][j], 0, 0, 0);
        __syncthreads();
    }

    #pragma unroll
    for (int j = 0; j < 4; ++j) {
        const int col = blockIdx.x * 128 + wn + j * 16 + fr;
        const float bv = bias[col];
        #pragma unroll
        for (int i = 0; i < 4; ++i) {
            const int row = blockIdx.y * 128 + wm + i * 16 + fq * 4;
            #pragma unroll
            for (int r = 0; r < 4; ++r)
                C[(size_t)(row + r) * N + col] = (OutT)(acc[i][j][r] + bv);
        }
    }
}

// ---------------------------------------------------------------------------
// MFMA periodic-sparse attention. One block = (b,h, residue r, 64-query tile).
// 4 waves x 16 q-rows. Per 64-key tile: S=QK^T (8 MFMAs/wave), online softmax
// in registers, P->LDS (A-layout), O+=PV (8 MFMAs/wave).
// K staged [key][72] fp16; V staged transposed Vt[d][72] fp16.
// ---------------------------------------------------------------------------
__global__ __launch_bounds__(256) void attn_mfma_kernel(
    const _Float16* __restrict__ qkv, const int* __restrict__ periods,
    _Float16* __restrict__ ao)
{
    constexpr int LDK = 72;   // padded stride (halves)
    __shared__ __align__(16) _Float16 Ks [64 * LDK];   // [key][d]
    __shared__ __align__(16) _Float16 Vts[64 * LDK];   // [d][key]
    __shared__ __align__(16) _Float16 Ps [64 * LDK];   // [q][key]

    const int bh = blockIdx.y;
    const int h  = bh & (H_ - 1);
    const int b  = bh >> 4;
    int p = periods[bh]; if (p < 1) p = 1;

    int tidx = blockIdx.x;
    int r = -1, q0 = 0, nr = 0;
    for (int rr = 0; rr < p; ++rr) {
        const int n  = (T_ - 1 - rr) / p + 1;
        const int nt = (n + 63) >> 6;
        if (tidx < nt) { r = rr; nr = n; q0 = tidx << 6; break; }
        tidx -= nt;
    }
    if (r < 0) return;
    const int qn = min(64, nr - q0);

    const int tid  = threadIdx.x;
    const int lane = tid & 63;
    const int w    = tid >> 6;        // wave id: q rows [w*16, w*16+16)
    const int ln   = lane & 15;       // MFMA m/n index
    const int fq   = lane >> 4;       // MFMA k-quad

    const size_t rowstride = 3 * (size_t)D_;
    const _Float16* base = qkv + (size_t)b * T_ * rowstride + h * HD_;

    // ---- Q A-fragments (loaded once): A[m=ln][k=fq*8+j], k-halves 0/1 ----
    half8 aq[2];
    {
        const int qq = w * 16 + ln;
        const int qi = min(q0 + qq, nr - 1);
        const _Float16* qrow = base + (size_t)(r + qi * p) * rowstride;
        aq[0] = *(const half8*)(qrow + fq * 8);
        aq[1] = *(const half8*)(qrow + 32 + fq * 8);
    }

    // accumulators: Od[nt][reg] = O[q=fq*4+reg][d=nt*16+ln]
    f32x4 Od[4];
    float m_i[4], l_i[4];
    #pragma unroll
    for (int nt = 0; nt < 4; ++nt)
        #pragma unroll
        for (int rr = 0; rr < 4; ++rr) Od[nt][rr] = 0.f;
    #pragma unroll
    for (int rr = 0; rr < 4; ++rr) { m_i[rr] = -INFINITY; l_i[rr] = 0.f; }

    // staging assignments
    const int kkK = tid >> 2, segK = tid & 3;      // K: 4 thr/row, 16 halves each
    const int kkV = tid & 63, dbV = tid >> 6;      // V: row kkV, d-block dbV*16

    const int kts = (q0 + qn + 63) >> 6;
    for (int kt = 0; kt < kts; ++kt) {
        const int k0 = kt << 6;

        __syncthreads();   // prior iter's MFMA reads of Ks/Vts done

        {   // ---- stage K [key][d] ----
            const int kj = min(k0 + kkK, nr - 1);
            const _Float16* krow = base + D_ + (size_t)(r + kj * p) * rowstride + segK * 16;
            half8 k0v = *(const half8*)(krow);
            half8 k1v = *(const half8*)(krow + 8);
            *(half8*)&Ks[kkK * LDK + segK * 16]     = k0v;
            *(half8*)&Ks[kkK * LDK + segK * 16 + 8] = k1v;
        }
        {   // ---- stage V transposed: Vt[d][key] ----
            const int kj = min(k0 + kkV, nr - 1);
            const _Float16* vrow = base + 2 * D_ + (size_t)(r + kj * p) * rowstride + dbV * 16;
            half8 v0 = *(const half8*)(vrow);
            half8 v1 = *(const half8*)(vrow + 8);
            #pragma unroll
            for (int c = 0; c < 8; ++c)
                Vts[(dbV * 16 + c) * LDK + kkV] = v0[c];
            #pragma unroll
            for (int c = 0; c < 8; ++c)
                Vts[(dbV * 16 + 8 + c) * LDK + kkV] = v1[c];
        }
        __syncthreads();

        // ---- S = Q K^T : Sd[nt][reg] = S[q=fq*4+reg][key=nt*16+ln] ----
        f32x4 Sd[4];
        #pragma unroll
        for (int nt = 0; nt < 4; ++nt) {
            #pragma unroll
            for (int rr = 0; rr < 4; ++rr) Sd[nt][rr] = 0.f;
            half8 bk0 = *(const half8*)&Ks[(nt * 16 + ln) * LDK + fq * 8];
            half8 bk1 = *(const half8*)&Ks[(nt * 16 + ln) * LDK + 32 + fq * 8];
            Sd[nt] = __builtin_amdgcn_mfma_f32_16x16x32_f16(aq[0], bk0, Sd[nt], 0, 0, 0);
            Sd[nt] = __builtin_amdgcn_mfma_f32_16x16x32_f16(aq[1], bk1, Sd[nt], 0, 0, 0);
        }

        // ---- scale + causal mask ----
        const bool diag = (k0 + 64 > q0);
        #pragma unroll
        for (int nt = 0; nt < 4; ++nt) {
            #pragma unroll
            for (int rr = 0; rr < 4; ++rr) {
                float s = Sd[nt][rr] * 0.125f;
                if (diag) {
                    const int q_abs = q0 + w * 16 + fq * 4 + rr;
                    const int k_abs = k0 + nt * 16 + ln;
                    if (k_abs > q_abs) s = -INFINITY;
                }
                Sd[nt][rr] = s;
            }
        }

        // ---- online softmax per q-row (rows live in the 16-lane ln-group) ----
        #pragma unroll
        for (int rr = 0; rr < 4; ++rr) {
            float v = fmaxf(fmaxf(Sd[0][rr], Sd[1][rr]), fmaxf(Sd[2][rr], Sd[3][rr]));
            v = fmaxf(v, __shfl_xor(v, 1));
            v = fmaxf(v, __shfl_xor(v, 2));
            v = fmaxf(v, __shfl_xor(v, 4));
            v = fmaxf(v, __shfl_xor(v, 8));
            const float newm  = fmaxf(m_i[rr], v);
            const float alpha = (newm == -INFINITY) ? 0.f : __expf(m_i[rr] - newm);
            m_i[rr] = newm;

            float e[4], lsum = 0.f;
            #pragma unroll
            for (int nt = 0; nt < 4; ++nt) {
                e[nt] = (newm == -INFINITY) ? 0.f : __expf(Sd[nt][rr] - newm);
                lsum += e[nt];
            }
            lsum += __shfl_xor(lsum, 1);
            lsum += __shfl_xor(lsum, 2);
            lsum += __shfl_xor(lsum, 4);
            lsum += __shfl_xor(lsum, 8);
            l_i[rr] = l_i[rr] * alpha + lsum;

            #pragma unroll
            for (int nt = 0; nt < 4; ++nt) {
                Od[nt][rr] *= alpha;
                Ps[(w * 16 + fq * 4 + rr) * LDK + nt * 16 + ln] = (_Float16)e[nt];
            }
        }
        // P is wave-private (rows [w*16,w*16+16)) -> no __syncthreads needed;
        // compiler inserts lgkmcnt wait before the dependent reads below.

        // ---- O += P V ----
        half8 ap0 = *(const half8*)&Ps[(w * 16 + ln) * LDK + fq * 8];
        half8 ap1 = *(const half8*)&Ps[(w * 16 + ln) * LDK + 32 + fq * 8];
        #pragma unroll
        for (int nt = 0; nt < 4; ++nt) {
            half8 bv0 = *(const half8*)&Vts[(nt * 16 + ln) * LDK + fq * 8];
            half8 bv1 = *(const half8*)&Vts[(nt * 16 + ln) * LDK + 32 + fq * 8];
            Od[nt] = __builtin_amdgcn_mfma_f32_16x16x32_f16(ap0, bv0, Od[nt], 0, 0, 0);
            Od[nt] = __builtin_amdgcn_mfma_f32_16x16x32_f16(ap1, bv1, Od[nt], 0, 0, 0);
        }
    }

    // ---- normalize + store: row q=fq*4+rr, col d=nt*16+ln ----
    #pragma unroll
    for (int rr = 0; rr < 4; ++rr) {
        const int qq = w * 16 + fq * 4 + rr;
        if (q0 + qq < nr) {
            const int i = r + (q0 + qq) * p;
            const float inv = 1.f / l_i[rr];
            _Float16* orow = ao + (size_t)(b * T_ + i) * D_ + h * HD_;
            #pragma unroll
            for (int nt = 0; nt < 4; ++nt)
                orow[nt * 16 + ln] = (_Float16)(Od[nt][rr] * inv);
        }
    }
}

// ---------------------------------------------------------------------------
extern "C" void kernel_launch(void* const* d_in, const int* in_sizes, int n_in,
                              void* d_out, int out_size, void* d_ws, size_t ws_size,
                              hipStream_t stream)
{
    const float* x       = (const float*)d_in[0];
    const int*   periods = (const int*)  d_in[1];
    const float* w_qkv   = (const float*)d_in[2];
    const float* b_qkv   = (const float*)d_in[3];
    const float* w_out   = (const float*)d_in[4];
    const float* b_out   = (const float*)d_in[5];
    float*       out     = (float*)d_out;

    const int M = B_ * T_;                                  // 4096

    _Float16* x16   = (_Float16*)d_ws;                      // 8 MB
    _Float16* wqkvT = x16   + (size_t)M * D_;               // 6 MB  [3D][D]
    _Float16* qkv16 = wqkvT + (size_t)(3 * D_) * D_;        // 24 MB [M][3D]
    _Float16* ao16  = qkv16 + (size_t)M * 3 * D_;           // 8 MB  [M][D]
    _Float16* woutT = ao16  + (size_t)M * D_;               // 2 MB  [D][D]

    cast_f32_f16_kernel<<<(M * D_) / (256 * 4), 256, 0, stream>>>(x, x16, M * D_);
    transpose_cast_kernel<<<dim3((3 * D_) / 32, D_ / 32), 256, 0, stream>>>(
        w_qkv, wqkvT, D_, 3 * D_);
    transpose_cast_kernel<<<dim3(D_ / 32, D_ / 32), 256, 0, stream>>>(
        w_out, woutT, D_, D_);

    // 1) qkv = x @ w_qkv + b_qkv   (f16 MFMA, f16 out)
    gemm_bt_f16<_Float16><<<dim3((3 * D_) / 128, M / 128), 256, 0, stream>>>(
        x16, wqkvT, b_qkv, qkv16, M, 3 * D_, D_);

    // 2) periodic sparse attention -> ao16 (MFMA)
    attn_mfma_kernel<<<dim3(48, B_ * H_), 256, 0, stream>>>(qkv16, periods, ao16);

    // 3) out = ao @ w_out + b_out  (f16 MFMA, fp32 out)
    gemm_bt_f16<float><<<dim3(D_ / 128, M / 128), 256, 0, stream>>>(
        ao16, woutT, b_out, out, M, D_, D_);
}